// Round 7
// baseline (83219.275 us; speedup 1.0000x reference)
//
#include <hip/hip_runtime.h>
#include <math.h>

// Problem constants: B=128, L=512, D_IN=512, D_H=1024, D_OUT=256
#define B_   128
#define L_   512
#define DIN  512
#define DH   1024
#define DOUT 256

#define NBLK 256
#define NTHR 1024

typedef float f32x4 __attribute__((ext_vector_type(4)));

__device__ __forceinline__ float hload(const float* p) {
  return __hip_atomic_load(p, __ATOMIC_RELAXED, __HIP_MEMORY_SCOPE_AGENT);
}
__device__ __forceinline__ void hstore(float* p, float v) {
  __hip_atomic_store(p, v, __ATOMIC_RELAXED, __HIP_MEMORY_SCOPE_AGENT);
}

// Persistent fused RNN, 128-VGPR-by-construction plan.
// Grid 256 x 1024. LDS 128 KB -> 1 block/CU, all 256 blocks co-resident.
// A 1024-thread workgroup NEEDS 4 waves/SIMD, so the VGPR cap is exactly 128;
// per-thread live set is ~100 (wrec 32 + win 16 + acc 16 + transients).
// Block: m-tile = (bid&7)*16 rows of B, n-tile = (bid>>3)*32 cols of H.
// Thread: no = tid&31 (1 col), ks = tid>>5 (1 of 32 k-slices: 32 rec-k / 16 in-k).
// Step l: h_new = tanh(X_l W_in1^T + (l>=2 ? h W_rec1^T : 0) + b_in1).
// All LDS reads are 2-address wave broadcasts (conflict-free, no swizzle).
// h exchanged via agent-scope atomics; per-m-group barrier (its 32 writer
// blocks are exactly its 32 reader blocks).
__global__ __launch_bounds__(NTHR) void rnn_persist(
    const float* __restrict__ X, const float* __restrict__ W_in1,
    const float* __restrict__ b_in1, const float* __restrict__ W_rec1,
    const float* __restrict__ W_out, const float* __restrict__ b_out,
    float* __restrict__ hA, float* __restrict__ hB,
    unsigned* __restrict__ bar, float* __restrict__ Y) {
  __shared__ __align__(16) float Hs[16 * 1024];  // 64 KB, linear
  __shared__ __align__(16) float Xs[16 * 512];   // 32 KB, linear
  __shared__ __align__(16) float Red[16 * 512];  // 32 KB [wave][m*32+no]

  const int tid   = (int)threadIdx.x;
  const int bid   = (int)blockIdx.x;
  const int m0    = (bid & 7) * 16;
  const int n0    = (bid >> 3) * 32;
  const int lane  = tid & 63;
  const int no    = tid & 31;
  const int ks    = tid >> 5;   // 0..31
  const int wavei = tid >> 6;   // 0..15

  // ---- register-resident weight slices (loaded once; row-contiguous) ----
  f32x4 wr4[8], wi4[4];
  {
    const float* wr = W_rec1 + (size_t)(n0 + no) * DH + ks * 32;
#pragma unroll
    for (int j = 0; j < 8; ++j) wr4[j] = *(const f32x4*)(wr + j * 4);
    const float* wi = W_in1 + (size_t)(n0 + no) * DIN + ks * 16;
#pragma unroll
    for (int j = 0; j < 4; ++j) wi4[j] = *(const f32x4*)(wi + j * 4);
  }
  const float bi = b_in1[n0 + no];  // (tid&31) column bias; used by tid<512

  unsigned phase = 0;
#pragma unroll 1
  for (int l = 1; l < L_; ++l) {
    const float* hp = (l & 1) ? hB : hA;
    float* hn       = (l & 1) ? hA : hB;

    // issue coherent h loads first; their wait lands after proj (latency hidden)
    float hreg[16];
    if (l > 1) {
      const float* hsrc = hp + (size_t)m0 * DH;  // this block's 16 rows (64 KB)
#pragma unroll
      for (int i = 0; i < 16; ++i) hreg[i] = hload(hsrc + tid + i * NTHR);
    }
    // stage X[:, l, :] tile: 8192 floats = 1024 thr x 2 x f32x4, linear
#pragma unroll
    for (int p = 0; p < 2; ++p) {
      const int idx = tid * 4 + p * 4096;
      const int m = idx >> 9, k = idx & 511;
      *(f32x4*)&Xs[idx] =
          *(const f32x4*)&X[((size_t)(m0 + m) * L_ + l) * DIN + k];
    }
    __syncthreads();

    // ---- proj partials: acc[m] = X[m][ks*16..+16) . win ----
    float accm[16];
#pragma unroll
    for (int m = 0; m < 16; ++m) {
      const f32x4* xr = (const f32x4*)&Xs[m * 512 + ks * 16];
      float s0 = 0.f, s1 = 0.f;
#pragma unroll
      for (int j = 0; j < 4; ++j) {
        const f32x4 x4 = xr[j];
        s0 += x4[0] * wi4[j][0]; s1 += x4[1] * wi4[j][1];
        s0 += x4[2] * wi4[j][2]; s1 += x4[3] * wi4[j][3];
      }
      accm[m] = s0 + s1;
    }

    if (l > 1) {
      // publish h to LDS (linear), then recurrent partials
#pragma unroll
      for (int i = 0; i < 16; ++i) Hs[tid + i * NTHR] = hreg[i];
      __syncthreads();
#pragma unroll
      for (int m = 0; m < 16; ++m) {
        const f32x4* hr = (const f32x4*)&Hs[m * 1024 + ks * 32];
        float s0 = accm[m], s1 = 0.f;
#pragma unroll
        for (int j = 0; j < 8; ++j) {
          const f32x4 h4 = hr[j];
          s0 += h4[0] * wr4[j][0]; s1 += h4[1] * wr4[j][1];
          s0 += h4[2] * wr4[j][2]; s1 += h4[3] * wr4[j][3];
        }
        accm[m] = s0 + s1;
      }
    }

    // ---- reduce: pair k-slices in-wave, then 16 partials via Red ----
#pragma unroll
    for (int m = 0; m < 16; ++m) accm[m] += __shfl_xor(accm[m], 32);
    if (lane < 32) {
#pragma unroll
      for (int m = 0; m < 16; ++m) Red[wavei * 512 + m * 32 + no] = accm[m];
    }
    __syncthreads();

    // ---- finalize (tid<512): sum 16 partials, bias, tanh, coherent store ----
    if (tid < 512) {
      const int mo = tid >> 5, nf = tid & 31;
      float s = 0.f;
#pragma unroll
      for (int w = 0; w < 16; ++w) s += Red[w * 512 + mo * 32 + nf];
      hstore(hn + (size_t)(m0 + mo) * DH + n0 + nf, tanhf(s + bi));
    }
    // ---- per-m-group barrier (32 blocks with this bid&7) ----
    __threadfence();
    __syncthreads();
    ++phase;
    if (tid == 0) {
      unsigned* ctr = bar + (size_t)(bid & 7) * 32;  // 128 B apart
      __hip_atomic_fetch_add(ctr, 1u, __ATOMIC_ACQ_REL, __HIP_MEMORY_SCOPE_AGENT);
      const unsigned tgt = phase * 32u;
      while (__hip_atomic_load(ctr, __ATOMIC_ACQUIRE, __HIP_MEMORY_SCOPE_AGENT) < tgt)
        __builtin_amdgcn_s_sleep(1);
    }
    __syncthreads();
  }

  // ---- output layer: Y = tanh(h_final @ W_out^T + b_out); h_final = hA ----
  if (bid < 64) {
    const int n0o = (bid >> 3) * 32;
    f32x4 wo4[8];
    const float* wr = W_out + (size_t)(n0o + no) * DH + ks * 32;
#pragma unroll
    for (int j = 0; j < 8; ++j) wo4[j] = *(const f32x4*)(wr + j * 4);

    const float* hsrc = hA + (size_t)m0 * DH;
    float hreg[16];
#pragma unroll
    for (int i = 0; i < 16; ++i) hreg[i] = hload(hsrc + tid + i * NTHR);
#pragma unroll
    for (int i = 0; i < 16; ++i) Hs[tid + i * NTHR] = hreg[i];
    __syncthreads();

    float accm[16];
#pragma unroll
    for (int m = 0; m < 16; ++m) {
      const f32x4* hr = (const f32x4*)&Hs[m * 1024 + ks * 32];
      float s0 = 0.f, s1 = 0.f;
#pragma unroll
      for (int j = 0; j < 8; ++j) {
        const f32x4 h4 = hr[j];
        s0 += h4[0] * wo4[j][0]; s1 += h4[1] * wo4[j][1];
        s0 += h4[2] * wo4[j][2]; s1 += h4[3] * wo4[j][3];
      }
      accm[m] = s0 + s1;
    }
#pragma unroll
    for (int m = 0; m < 16; ++m) accm[m] += __shfl_xor(accm[m], 32);
    if (lane < 32) {
#pragma unroll
      for (int m = 0; m < 16; ++m) Red[wavei * 512 + m * 32 + no] = accm[m];
    }
    __syncthreads();
    if (tid < 512) {
      const int mo = tid >> 5, nf = tid & 31;
      float s = 0.f;
#pragma unroll
      for (int w = 0; w < 16; ++w) s += Red[w * 512 + mo * 32 + nf];
      Y[(size_t)(m0 + mo) * DOUT + n0o + nf] = tanhf(s + b_out[n0o + nf]);
    }
  }
}

extern "C" void kernel_launch(void* const* d_in, const int* in_sizes, int n_in,
                              void* d_out, int out_size, void* d_ws, size_t ws_size,
                              hipStream_t stream) {
  const float* X      = (const float*)d_in[0];
  const float* W_in1  = (const float*)d_in[1];
  const float* b_in1  = (const float*)d_in[2];
  const float* W_rec1 = (const float*)d_in[3];
  // d_in[4..6] = W_in2/b_in2/W_rec2 : dead code w.r.t. Y
  const float* W_out  = (const float*)d_in[7];
  const float* b_out  = (const float*)d_in[8];
  float* out = (float*)d_out;

  // ws layout: [0,4096): 8 group-barrier counters (128 B apart); then hA, hB
  unsigned* bar = (unsigned*)d_ws;
  float* hA = (float*)((char*)d_ws + 4096);
  float* hB = hA + (size_t)B_ * DH;

  hipMemsetAsync(d_ws, 0, 4096, stream);  // reset barriers each launch (replay-safe)
  rnn_persist<<<NBLK, NTHR, 0, stream>>>(X, W_in1, b_in1, W_rec1, W_out, b_out,
                                         hA, hB, bar, out);
}

// Round 8
// 45882.361 us; speedup vs baseline: 1.8138x; 1.8138x over previous
//
#include <hip/hip_runtime.h>
#include <math.h>

// Problem constants: B=128, L=512, D_IN=512, D_H=1024, D_OUT=256
#define B_   128
#define L_   512
#define DIN  512
#define DH   1024
#define DOUT 256

#define NBLK 256
#define NTHR 256   // 256 thr/block is the ONLY size hipcc grants 256 VGPRs (R3/R5/R7 evidence)

typedef float f32x4 __attribute__((ext_vector_type(4)));

__device__ __forceinline__ float hload(const float* p) {
  return __hip_atomic_load(p, __ATOMIC_RELAXED, __HIP_MEMORY_SCOPE_AGENT);
}
__device__ __forceinline__ void hstore(float* p, float v) {
  __hip_atomic_store(p, v, __ATOMIC_RELAXED, __HIP_MEMORY_SCOPE_AGENT);
}

// Persistent fused RNN, fits a 256-VGPR wave by design (~235 peak live).
// Grid 256 x 256. LDS 104 KB -> 1 block/CU, all 256 blocks co-resident.
// Block: m-tile = (bid&7)*16 rows of B, n-tile = (bid>>3)*32 cols of H.
// Thread: cg = tid&31 (owns 1 column), ks = tid>>5 (1 of 8 k-slices).
// Register W: wrec row-slice 128 f32 + win row-slice 64 f32 = 192; acc[16].
// h staging: global->LDS via 32-float transient groups (lifetime disjoint from acc).
// Step l: h_new = tanh(X_l W_in1^T + (l>=2 ? h W_rec1^T : 0) + b_in1).
// h exchanged via agent-scope atomics; per-m-group barrier (32 blocks).
__global__ __launch_bounds__(NTHR, 1) void rnn_persist(
    const float* __restrict__ X, const float* __restrict__ W_in1,
    const float* __restrict__ b_in1, const float* __restrict__ W_rec1,
    const float* __restrict__ W_out, const float* __restrict__ b_out,
    float* __restrict__ hA, float* __restrict__ hB,
    unsigned* __restrict__ bar, float* __restrict__ Y) {
  __shared__ __align__(16) float Hs[16 * 1024];  // 64 KB, linear
  __shared__ __align__(16) float Xs[16 * 512];   // 32 KB, linear
  __shared__ __align__(16) float Red[4 * 512];   //  8 KB [wavepair][m*32+col]

  const int tid  = (int)threadIdx.x;
  const int bid  = (int)blockIdx.x;
  const int m0   = (bid & 7) * 16;
  const int n0   = (bid >> 3) * 32;
  const int cg   = tid & 31;     // column within n-tile
  const int ks   = tid >> 5;     // k-slice 0..7 (rec: 128 elems, in: 64 elems)
  const int wv   = tid >> 6;     // wave 0..3

  // ---- register-resident weight slices (row-contiguous vec4 loads) ----
  f32x4 wr4[32], wi4[16];
  {
    const float* wr = W_rec1 + (size_t)(n0 + cg) * DH + ks * 128;
#pragma unroll
    for (int j = 0; j < 32; ++j) wr4[j] = *(const f32x4*)(wr + j * 4);
    const float* wi = W_in1 + (size_t)(n0 + cg) * DIN + ks * 64;
#pragma unroll
    for (int j = 0; j < 16; ++j) wi4[j] = *(const f32x4*)(wi + j * 4);
  }
  // finalize-phase constants: 2 outputs/thread
  const int mo = tid >> 4;             // 0..15
  const int no = (tid & 15) << 1;      // even col
  const float bi0 = b_in1[n0 + no], bi1 = b_in1[n0 + no + 1];

  unsigned phase = 0;
#pragma unroll 1
  for (int l = 1; l < L_; ++l) {
    const float* hp = (l & 1) ? hB : hA;
    float* hn       = (l & 1) ? hA : hB;

    // ---- stage X[:, l, :] tile: 8192 floats = 256 thr x 8 x f32x4 ----
#pragma unroll
    for (int p = 0; p < 8; ++p) {
      const int e = (tid + p * NTHR) * 4;       // == m*512 + k
      const int m = e >> 9, k = e & 511;
      *(f32x4*)&Xs[e] = *(const f32x4*)&X[((size_t)(m0 + m) * L_ + l) * DIN + k];
    }
    // ---- stage h tile: 16384 floats, 2 groups of 32 scalars/thread ----
    if (l > 1) {
      const float* hsrc = hp + (size_t)m0 * DH;
#pragma unroll 1
      for (int g = 0; g < 2; ++g) {
        float t[32];
#pragma unroll
        for (int i = 0; i < 32; ++i)
          t[i] = hload(hsrc + tid + (g * 32 + i) * NTHR);
#pragma unroll
        for (int i = 0; i < 32; ++i) Hs[tid + (g * 32 + i) * NTHR] = t[i];
      }
    }
    __syncthreads();

    // ---- proj partials: acc[m] = X[m][ks*64 .. +64) . win ----
    float acc[16];
#pragma unroll
    for (int m = 0; m < 16; ++m) {
      const f32x4* xr = (const f32x4*)&Xs[m * 512 + ks * 64];
      float s0 = 0.f, s1 = 0.f, s2 = 0.f, s3 = 0.f;
#pragma unroll
      for (int j = 0; j < 16; ++j) {
        const f32x4 x4 = xr[j];
        s0 += x4[0] * wi4[j][0]; s1 += x4[1] * wi4[j][1];
        s2 += x4[2] * wi4[j][2]; s3 += x4[3] * wi4[j][3];
      }
      acc[m] = (s0 + s1) + (s2 + s3);
    }
    // ---- recurrent partials: acc[m] += h[m][ks*128 .. +128) . wrec ----
    if (l > 1) {
#pragma unroll
      for (int m = 0; m < 16; ++m) {
        const f32x4* hr = (const f32x4*)&Hs[m * 1024 + ks * 128];
        float s0 = 0.f, s1 = 0.f, s2 = 0.f, s3 = 0.f;
#pragma unroll
        for (int j = 0; j < 32; ++j) {
          const f32x4 h4 = hr[j];
          s0 += h4[0] * wr4[j][0]; s1 += h4[1] * wr4[j][1];
          s2 += h4[2] * wr4[j][2]; s3 += h4[3] * wr4[j][3];
        }
        acc[m] += (s0 + s1) + (s2 + s3);
      }
    }

    // ---- reduce 8 k-slices: pair in-wave, then 4 partials via Red ----
#pragma unroll
    for (int m = 0; m < 16; ++m) acc[m] += __shfl_xor(acc[m], 32);
    if ((tid & 63) < 32) {
#pragma unroll
      for (int m = 0; m < 16; ++m) Red[wv * 512 + m * 32 + cg] = acc[m];
    }
    __syncthreads();

    // ---- finalize 2 outputs/thread: sum 4 partials, bias, tanh, store ----
    {
      float s0 = 0.f, s1 = 0.f;
#pragma unroll
      for (int w = 0; w < 4; ++w) {
        const float2 r = *(const float2*)&Red[w * 512 + mo * 32 + no];
        s0 += r.x; s1 += r.y;
      }
      float* hw = hn + (size_t)(m0 + mo) * DH + n0 + no;
      hstore(hw,     tanhf(s0 + bi0));
      hstore(hw + 1, tanhf(s1 + bi1));
    }
    // ---- per-m-group barrier (32 blocks with this bid&7) ----
    __threadfence();
    __syncthreads();
    ++phase;
    if (tid == 0) {
      unsigned* ctr = bar + (size_t)(bid & 7) * 32;  // 128 B apart
      __hip_atomic_fetch_add(ctr, 1u, __ATOMIC_ACQ_REL, __HIP_MEMORY_SCOPE_AGENT);
      const unsigned tgt = phase * 32u;
      while (__hip_atomic_load(ctr, __ATOMIC_ACQUIRE, __HIP_MEMORY_SCOPE_AGENT) < tgt)
        __builtin_amdgcn_s_sleep(1);
    }
    __syncthreads();
  }

  // ---- output layer: Y = tanh(h_final @ W_out^T + b_out); h_final = hA ----
  if (bid < 64) {
    const int n0o = (bid >> 3) * 32;
    f32x4 wo4[32];
    const float* wr = W_out + (size_t)(n0o + cg) * DH + ks * 128;
#pragma unroll
    for (int j = 0; j < 32; ++j) wo4[j] = *(const f32x4*)(wr + j * 4);

    const float* hsrc = hA + (size_t)m0 * DH;
#pragma unroll 1
    for (int g = 0; g < 2; ++g) {
      float t[32];
#pragma unroll
      for (int i = 0; i < 32; ++i)
        t[i] = hload(hsrc + tid + (g * 32 + i) * NTHR);
#pragma unroll
      for (int i = 0; i < 32; ++i) Hs[tid + (g * 32 + i) * NTHR] = t[i];
    }
    __syncthreads();

    float acc[16];
#pragma unroll
    for (int m = 0; m < 16; ++m) {
      const f32x4* hr = (const f32x4*)&Hs[m * 1024 + ks * 128];
      float s0 = 0.f, s1 = 0.f, s2 = 0.f, s3 = 0.f;
#pragma unroll
      for (int j = 0; j < 32; ++j) {
        const f32x4 h4 = hr[j];
        s0 += h4[0] * wo4[j][0]; s1 += h4[1] * wo4[j][1];
        s2 += h4[2] * wo4[j][2]; s3 += h4[3] * wo4[j][3];
      }
      acc[m] = (s0 + s1) + (s2 + s3);
    }
#pragma unroll
    for (int m = 0; m < 16; ++m) acc[m] += __shfl_xor(acc[m], 32);
    if ((tid & 63) < 32) {
#pragma unroll
      for (int m = 0; m < 16; ++m) Red[wv * 512 + m * 32 + cg] = acc[m];
    }
    __syncthreads();
    {
      float s0 = 0.f, s1 = 0.f;
#pragma unroll
      for (int w = 0; w < 4; ++w) {
        const float2 r = *(const float2*)&Red[w * 512 + mo * 32 + no];
        s0 += r.x; s1 += r.y;
      }
      const int nc = n0o + no;
      Y[(size_t)(m0 + mo) * DOUT + nc]     = tanhf(s0 + b_out[nc]);
      Y[(size_t)(m0 + mo) * DOUT + nc + 1] = tanhf(s1 + b_out[nc + 1]);
    }
  }
}

extern "C" void kernel_launch(void* const* d_in, const int* in_sizes, int n_in,
                              void* d_out, int out_size, void* d_ws, size_t ws_size,
                              hipStream_t stream) {
  const float* X      = (const float*)d_in[0];
  const float* W_in1  = (const float*)d_in[1];
  const float* b_in1  = (const float*)d_in[2];
  const float* W_rec1 = (const float*)d_in[3];
  // d_in[4..6] = W_in2/b_in2/W_rec2 : dead code w.r.t. Y
  const float* W_out  = (const float*)d_in[7];
  const float* b_out  = (const float*)d_in[8];
  float* out = (float*)d_out;

  // ws layout: [0,4096): 8 group-barrier counters (128 B apart); then hA, hB
  unsigned* bar = (unsigned*)d_ws;
  float* hA = (float*)((char*)d_ws + 4096);
  float* hB = hA + (size_t)B_ * DH;

  hipMemsetAsync(d_ws, 0, 4096, stream);  // reset barriers each launch (replay-safe)
  rnn_persist<<<NBLK, NTHR, 0, stream>>>(X, W_in1, b_in1, W_rec1, W_out, b_out,
                                         hA, hB, bar, out);
}